// Round 1
// baseline (99.129 us; speedup 1.0000x reference)
//
#include <hip/hip_runtime.h>

#define NATOMS 4096
#define MAXP   32768
#define CUTOFF 5.0f
#define OUT_TOTAL (6 * MAXP)   // 65536 neighbors + 32768 dist + 98304 vecs

// ---------------------------------------------------------------------------
// K0: initialize the full output buffer every call (harness does not re-poison
// between replays). neighbors region = -1.0f, everything else = 0.0f.
// ---------------------------------------------------------------------------
__global__ void fill_k(float* __restrict__ out) {
    int idx = blockIdx.x * blockDim.x + threadIdx.x;
    if (idx < OUT_TOTAL) {
        out[idx] = (idx < 2 * MAXP) ? -1.0f : 0.0f;
    }
}

// ---------------------------------------------------------------------------
// K1: per-row count of valid pairs (j > i, same molecule, dist < CUTOFF).
// batch is sorted, so the row scan stops at the molecule boundary.
// ---------------------------------------------------------------------------
__global__ void count_k(const float* __restrict__ pos,
                        const int*   __restrict__ batch,
                        int*         __restrict__ cnt) {
#pragma clang fp contract(off)
    int i = blockIdx.x * blockDim.x + threadIdx.x;
    if (i >= NATOMS) return;
    const int   b  = batch[i];
    const float xi = pos[3 * i + 0];
    const float yi = pos[3 * i + 1];
    const float zi = pos[3 * i + 2];
    int c = 0;
    for (int j = i + 1; j < NATOMS; ++j) {
        if (batch[j] != b) break;
        float vx = xi - pos[3 * j + 0];
        float vy = yi - pos[3 * j + 1];
        float vz = zi - pos[3 * j + 2];
        float d2 = vx * vx + vy * vy + vz * vz;
        float d  = sqrtf(d2);
        if (d < CUTOFF) ++c;
    }
    cnt[i] = c;
}

// ---------------------------------------------------------------------------
// K2: exclusive prefix sum of the 4096 row counts. Single wave of 64 lanes,
// each lane owns 64 consecutive rows. Serial partial sum -> wave scan via
// shfl_up -> serial write of exclusive offsets.
// ---------------------------------------------------------------------------
__global__ void scan_k(const int* __restrict__ cnt, int* __restrict__ off) {
    int lane = threadIdx.x;          // 0..63
    int base = lane * 64;
    int s = 0;
    for (int k = 0; k < 64; ++k) s += cnt[base + k];
    // inclusive wave scan
    int inc = s;
    for (int o = 1; o < 64; o <<= 1) {
        int v = __shfl_up(inc, o);
        if (lane >= o) inc += v;
    }
    int excl = __shfl_up(inc, 1);
    if (lane == 0) excl = 0;
    int run = excl;
    for (int k = 0; k < 64; ++k) {
        off[base + k] = run;
        run += cnt[base + k];
    }
}

// ---------------------------------------------------------------------------
// K3: second pass — recompute distances in the same order and scatter each
// valid pair into slot = row_offset[i] + local_rank. Slot >= MAXP dropped
// (matches JAX scatter mode="drop"). Outputs written as float32 values.
// ---------------------------------------------------------------------------
__global__ void write_k(const float* __restrict__ pos,
                        const int*   __restrict__ batch,
                        const int*   __restrict__ off,
                        float*       __restrict__ out) {
#pragma clang fp contract(off)
    int i = blockIdx.x * blockDim.x + threadIdx.x;
    if (i >= NATOMS) return;
    const int   b  = batch[i];
    const float xi = pos[3 * i + 0];
    const float yi = pos[3 * i + 1];
    const float zi = pos[3 * i + 2];
    int slot = off[i];
    for (int j = i + 1; j < NATOMS; ++j) {
        if (batch[j] != b) break;
        float vx = xi - pos[3 * j + 0];
        float vy = yi - pos[3 * j + 1];
        float vz = zi - pos[3 * j + 2];
        float d2 = vx * vx + vy * vy + vz * vz;
        float d  = sqrtf(d2);
        if (d < CUTOFF) {
            if (slot < MAXP) {
                out[slot]            = (float)i;   // neighbors[0, slot]
                out[MAXP + slot]     = (float)j;   // neighbors[1, slot]
                out[2 * MAXP + slot] = d;          // distances[slot]
                float* v = out + 3 * MAXP + 3 * slot;
                v[0] = vx; v[1] = vy; v[2] = vz;   // distance_vecs[slot]
            }
            ++slot;
        }
    }
}

extern "C" void kernel_launch(void* const* d_in, const int* in_sizes, int n_in,
                              void* d_out, int out_size, void* d_ws, size_t ws_size,
                              hipStream_t stream) {
    const float* pos   = (const float*)d_in[0];   // [4096,3] f32
    const int*   batch = (const int*)d_in[1];     // [4096] i32 (sorted)
    float* out = (float*)d_out;                   // 196608 f32 (all outputs)

    int* cnt = (int*)d_ws;          // 4096 ints
    int* off = cnt + NATOMS;        // 4096 ints

    fill_k<<<(OUT_TOTAL + 255) / 256, 256, 0, stream>>>(out);
    count_k<<<(NATOMS + 255) / 256, 256, 0, stream>>>(pos, batch, cnt);
    scan_k<<<1, 64, 0, stream>>>(cnt, off);
    write_k<<<(NATOMS + 255) / 256, 256, 0, stream>>>(pos, batch, off, out);
}

// Round 2
// 21.189 us; speedup vs baseline: 4.6784x; 4.6784x over previous
//
#include <hip/hip_runtime.h>

#define NATOMS 4096
#define MAXP   32768
#define CUTOFF 5.0f
#define OUT_TOTAL (6 * MAXP)   // 65536 neighbors + 32768 dist + 98304 vecs

// ---------------------------------------------------------------------------
// K0: initialize the full output buffer every call (harness does not re-poison
// between replays). neighbors region = -1.0f, everything else = 0.0f.
// ---------------------------------------------------------------------------
__global__ void fill_k(float* __restrict__ out) {
    int idx = blockIdx.x * blockDim.x + threadIdx.x;
    if (idx < OUT_TOTAL) {
        out[idx] = (idx < 2 * MAXP) ? -1.0f : 0.0f;
    }
}

// Uniform helper: first index > i where batch[] != b (batch is sorted).
__device__ __forceinline__ int row_end(const int* __restrict__ batch, int i, int b) {
    int lo = i + 1, hi = NATOMS;
    while (lo < hi) {
        int mid = (lo + hi) >> 1;
        if (batch[mid] == b) lo = mid + 1; else hi = mid;
    }
    return lo;
}

// ---------------------------------------------------------------------------
// K1: per-row count of valid pairs. ONE WAVE PER ROW; lanes stride over j.
// ---------------------------------------------------------------------------
__global__ void count_k(const float* __restrict__ pos,
                        const int*   __restrict__ batch,
                        int*         __restrict__ cnt) {
#pragma clang fp contract(off)
    int wave = blockIdx.x * (blockDim.x >> 6) + (threadIdx.x >> 6);
    int lane = threadIdx.x & 63;
    if (wave >= NATOMS) return;
    const int i = wave;
    const int b = batch[i];
    const int end = row_end(batch, i, b);
    const float xi = pos[3 * i + 0];
    const float yi = pos[3 * i + 1];
    const float zi = pos[3 * i + 2];
    int c = 0;
    for (int j0 = i + 1; j0 < end; j0 += 64) {
        int j = j0 + lane;
        bool valid = false;
        if (j < end) {
            float vx = xi - pos[3 * j + 0];
            float vy = yi - pos[3 * j + 1];
            float vz = zi - pos[3 * j + 2];
            float d2 = vx * vx + vy * vy + vz * vz;
            valid = sqrtf(d2) < CUTOFF;
        }
        c += __popcll(__ballot(valid));
    }
    if (lane == 0) cnt[i] = c;
}

// ---------------------------------------------------------------------------
// K2: exclusive prefix sum of the 4096 row counts. Single wave of 64 lanes.
// ---------------------------------------------------------------------------
__global__ void scan_k(const int* __restrict__ cnt, int* __restrict__ off) {
    int lane = threadIdx.x;          // 0..63
    int base = lane * 64;
    int s = 0;
    for (int k = 0; k < 64; ++k) s += cnt[base + k];
    int inc = s;
    for (int o = 1; o < 64; o <<= 1) {
        int v = __shfl_up(inc, o);
        if (lane >= o) inc += v;
    }
    int excl = __shfl_up(inc, 1);
    if (lane == 0) excl = 0;
    int run = excl;
    for (int k = 0; k < 64; ++k) {
        off[base + k] = run;
        run += cnt[base + k];
    }
}

// ---------------------------------------------------------------------------
// K3: write pass. ONE WAVE PER ROW; lanes stride over j. Within-chunk rank
// via ballot prefix popcount keeps exact lexicographic slot order.
// ---------------------------------------------------------------------------
__global__ void write_k(const float* __restrict__ pos,
                        const int*   __restrict__ batch,
                        const int*   __restrict__ off,
                        float*       __restrict__ out) {
#pragma clang fp contract(off)
    int wave = blockIdx.x * (blockDim.x >> 6) + (threadIdx.x >> 6);
    int lane = threadIdx.x & 63;
    if (wave >= NATOMS) return;
    const int i = wave;
    const int b = batch[i];
    const int end = row_end(batch, i, b);
    const float xi = pos[3 * i + 0];
    const float yi = pos[3 * i + 1];
    const float zi = pos[3 * i + 2];
    int slotbase = off[i];
    for (int j0 = i + 1; j0 < end; j0 += 64) {
        int j = j0 + lane;
        bool valid = false;
        float vx = 0.f, vy = 0.f, vz = 0.f, d = 0.f;
        if (j < end) {
            vx = xi - pos[3 * j + 0];
            vy = yi - pos[3 * j + 1];
            vz = zi - pos[3 * j + 2];
            float d2 = vx * vx + vy * vy + vz * vz;
            d = sqrtf(d2);
            valid = d < CUTOFF;
        }
        unsigned long long m = __ballot(valid);
        if (valid) {
            int slot = slotbase + __popcll(m & ((1ULL << lane) - 1ULL));
            if (slot < MAXP) {
                out[slot]            = (float)i;   // neighbors[0, slot]
                out[MAXP + slot]     = (float)j;   // neighbors[1, slot]
                out[2 * MAXP + slot] = d;          // distances[slot]
                float* v = out + 3 * MAXP + 3 * slot;
                v[0] = vx; v[1] = vy; v[2] = vz;   // distance_vecs[slot]
            }
        }
        slotbase += __popcll(m);
    }
}

extern "C" void kernel_launch(void* const* d_in, const int* in_sizes, int n_in,
                              void* d_out, int out_size, void* d_ws, size_t ws_size,
                              hipStream_t stream) {
    const float* pos   = (const float*)d_in[0];   // [4096,3] f32
    const int*   batch = (const int*)d_in[1];     // [4096] i32 (sorted)
    float* out = (float*)d_out;                   // 196608 f32 (all outputs)

    int* cnt = (int*)d_ws;          // 4096 ints
    int* off = cnt + NATOMS;        // 4096 ints

    // 4096 waves -> 4 waves/block -> 1024 blocks
    fill_k <<<(OUT_TOTAL + 255) / 256, 256, 0, stream>>>(out);
    count_k<<<NATOMS / 4, 256, 0, stream>>>(pos, batch, cnt);
    scan_k <<<1, 64, 0, stream>>>(cnt, off);
    write_k<<<NATOMS / 4, 256, 0, stream>>>(pos, batch, off, out);
}

// Round 3
// 15.101 us; speedup vs baseline: 6.5645x; 1.4032x over previous
//
#include <hip/hip_runtime.h>

#define NATOMS 4096
#define MAXP   32768
#define CUTOFF 5.0f
#define OUT_TOTAL (6 * MAXP)   // 65536 neighbors + 32768 dist + 98304 vecs
#define NBLK    1024           // 4 rows per block, 4096 rows

// Uniform helper: first index > i where batch[] != b (batch is sorted).
__device__ __forceinline__ int row_end(const int* __restrict__ batch, int i, int b) {
    int lo = i + 1, hi = NATOMS;
    while (lo < hi) {
        int mid = (lo + hi) >> 1;
        if (batch[mid] == b) lo = mid + 1; else hi = mid;
    }
    return lo;
}

// ---------------------------------------------------------------------------
// K1: output-buffer init (grid exactly covers OUT_TOTAL) + per-row pair count.
// One wave per row, 4 rows per block; per-block sum stored for K2's scan.
// ---------------------------------------------------------------------------
__global__ void count_fill_k(const float* __restrict__ pos,
                             const int*   __restrict__ batch,
                             int*         __restrict__ cnt,
                             int*         __restrict__ bsum,
                             float*       __restrict__ out) {
#pragma clang fp contract(off)
    const int tid = threadIdx.x;
    const int p   = blockIdx.x;

    // --- fill slice: 1024 blocks * 256 threads = 262144 >= 196608 ---
    int idx = p * 256 + tid;
    if (idx < OUT_TOTAL) out[idx] = (idx < 2 * MAXP) ? -1.0f : 0.0f;

    // --- count: wave w of this block owns row i ---
    const int w    = tid >> 6;
    const int lane = tid & 63;
    const int i    = p * 4 + w;

    const int b   = batch[i];
    const int end = row_end(batch, i, b);
    const float xi = pos[3 * i + 0];
    const float yi = pos[3 * i + 1];
    const float zi = pos[3 * i + 2];

    int c = 0;
    for (int j0 = i + 1; j0 < end; j0 += 64) {
        int j = j0 + lane;
        bool valid = false;
        if (j < end) {
            float vx = xi - pos[3 * j + 0];
            float vy = yi - pos[3 * j + 1];
            float vz = zi - pos[3 * j + 2];
            float d2 = vx * vx + vy * vy + vz * vz;
            valid = sqrtf(d2) < CUTOFF;
        }
        c += __popcll(__ballot(valid));
    }

    __shared__ int ls[4];
    if (lane == 0) { cnt[i] = c; ls[w] = c; }
    __syncthreads();
    if (tid == 0) bsum[p] = ls[0] + ls[1] + ls[2] + ls[3];
}

// ---------------------------------------------------------------------------
// K2: each block redundantly computes its global exclusive prefix from bsum
// (strided loads + LDS tree reduce), then runs the ballot-ordered write pass.
// ---------------------------------------------------------------------------
__global__ void write_k(const float* __restrict__ pos,
                        const int*   __restrict__ batch,
                        const int*   __restrict__ cnt,
                        const int*   __restrict__ bsum,
                        float*       __restrict__ out) {
#pragma clang fp contract(off)
    const int tid = threadIdx.x;
    const int p   = blockIdx.x;

    __shared__ int red[256];
    int s = 0;
    for (int q = tid; q < p; q += 256) s += bsum[q];
    red[tid] = s;
    __syncthreads();
    for (int step = 128; step > 0; step >>= 1) {
        if (tid < step) red[tid] += red[tid + step];
        __syncthreads();
    }
    const int prefix = red[0];            // total pairs in rows of blocks < p

    const int w    = tid >> 6;
    const int lane = tid & 63;
    const int i    = p * 4 + w;

    int slotbase = prefix;
    for (int r = p * 4; r < i; ++r) slotbase += cnt[r];

    const int b   = batch[i];
    const int end = row_end(batch, i, b);
    const float xi = pos[3 * i + 0];
    const float yi = pos[3 * i + 1];
    const float zi = pos[3 * i + 2];

    for (int j0 = i + 1; j0 < end; j0 += 64) {
        int j = j0 + lane;
        bool valid = false;
        float vx = 0.f, vy = 0.f, vz = 0.f, d = 0.f;
        if (j < end) {
            vx = xi - pos[3 * j + 0];
            vy = yi - pos[3 * j + 1];
            vz = zi - pos[3 * j + 2];
            float d2 = vx * vx + vy * vy + vz * vz;
            d = sqrtf(d2);
            valid = d < CUTOFF;
        }
        unsigned long long m = __ballot(valid);
        if (valid) {
            int slot = slotbase + __popcll(m & ((1ULL << lane) - 1ULL));
            if (slot < MAXP) {
                out[slot]            = (float)i;   // neighbors[0, slot]
                out[MAXP + slot]     = (float)j;   // neighbors[1, slot]
                out[2 * MAXP + slot] = d;          // distances[slot]
                float* v = out + 3 * MAXP + 3 * slot;
                v[0] = vx; v[1] = vy; v[2] = vz;   // distance_vecs[slot]
            }
        }
        slotbase += __popcll(m);
    }
}

extern "C" void kernel_launch(void* const* d_in, const int* in_sizes, int n_in,
                              void* d_out, int out_size, void* d_ws, size_t ws_size,
                              hipStream_t stream) {
    const float* pos   = (const float*)d_in[0];   // [4096,3] f32
    const int*   batch = (const int*)d_in[1];     // [4096] i32 (sorted)
    float* out = (float*)d_out;                   // 196608 f32 (all outputs)

    int* cnt  = (int*)d_ws;          // 4096 ints
    int* bsum = cnt + NATOMS;        // 1024 ints

    count_fill_k<<<NBLK, 256, 0, stream>>>(pos, batch, cnt, bsum, out);
    write_k     <<<NBLK, 256, 0, stream>>>(pos, batch, cnt, bsum, out);
}